// Round 2
// baseline (224.673 us; speedup 1.0000x reference)
//
#include <hip/hip_runtime.h>

#define B_    8
#define CIN   128
#define COUT  128
#define NX    8192
#define KMJ   32
#define MODES 256

typedef short bf16x8 __attribute__((ext_vector_type(8)));
typedef float f32x4  __attribute__((ext_vector_type(4)));

__device__ __forceinline__ float bf2f(unsigned short u) {
    union { unsigned int i; float f; } v; v.i = ((unsigned int)u) << 16; return v.f;
}
__device__ __forceinline__ unsigned short f2bf(float f) {
    union { float f; unsigned int i; } v; v.f = f;
    unsigned int x = v.i;
    return (unsigned short)((x + 0x7fffu + ((x >> 16) & 1u)) >> 16);
}
__device__ __forceinline__ bf16x8 cvt8(const float* __restrict__ p) {
    f32x4 a = *(const f32x4*)p;
    f32x4 b = *(const f32x4*)(p + 4);
    bf16x8 r;
    r[0] = (short)f2bf(a[0]); r[1] = (short)f2bf(a[1]);
    r[2] = (short)f2bf(a[2]); r[3] = (short)f2bf(a[3]);
    r[4] = (short)f2bf(b[0]); r[5] = (short)f2bf(b[1]);
    r[6] = (short)f2bf(b[2]); r[7] = (short)f2bf(b[3]);
    return r;
}
__device__ __forceinline__ ushort4 cvt4(f32x4 a) {
    ushort4 r;
    r.x = f2bf(a[0]); r.y = f2bf(a[1]); r.z = f2bf(a[2]); r.w = f2bf(a[3]);
    return r;
}

// ---------------------------------------------------------------------------
// K1 v2: Wk[k][o][i] = sum_j D[j][k] * weights[i][o][j]   (unchanged)
// ---------------------------------------------------------------------------
__global__ __launch_bounds__(256) void k1_wk(const float* __restrict__ W,
                                             const float* __restrict__ D,
                                             unsigned short* __restrict__ Wk) {
    int wave = threadIdx.x >> 6, lane = threadIdx.x & 63;
    int quad = lane >> 4, l16 = lane & 15;
    int gw  = blockIdx.x * 4 + wave;
    int oi0 = gw * 16;
    int i0  = oi0 & 127, o0 = oi0 >> 7;
    bf16x8 bfrag = cvt8(W + ((size_t)(i0 + l16) * COUT + o0) * KMJ + quad * 8);
    for (int mt = 0; mt < 16; mt++) {
        int k0 = mt * 16;
        bf16x8 afrag;
#pragma unroll
        for (int jj = 0; jj < 8; jj++)
            afrag[jj] = (short)f2bf(D[(quad * 8 + jj) * MODES + k0 + l16]);
        f32x4 acc = {0.f, 0.f, 0.f, 0.f};
        acc = __builtin_amdgcn_mfma_f32_16x16x32_bf16(afrag, bfrag, acc, 0, 0, 0);
#pragma unroll
        for (int r = 0; r < 4; r++)
            Wk[(size_t)(k0 + quad * 4 + r) * (CIN * COUT) + oi0 + l16] = f2bf(acc[r]);
    }
}

// ---------------------------------------------------------------------------
// K2 v5: PART[b][nt][c][k] = sum_{n in nt-chunk} x[b][c][n]*wb[b][n][k]  (bf16)
//
// Round-1 post-mortem: v3 (100MB/45us) and v4 (134MB/46us, 2x occupancy)
// timed identically with FETCH_SIZE byte-identical -> MLP/latency-limited:
// only 4x16B in flight per thread, flushed by vmcnt(0) at every barrier
// (16 barrier-drains/block).  v5: 4 fat passes of 64 n.  Per pass each
// thread bursts 8x16B loads with NO barrier in between (compiler emits
// counted vmcnt waits), and the next pass's burst is issued right after the
// staging barrier so it drains across the whole compute phase.  Barriers
// 16 -> 8.  In-flight bytes/CU ~4KB -> ~128KB.
// Accumulation order over n identical to v4 -> bitwise-same PART.
// ---------------------------------------------------------------------------
__global__ __launch_bounds__(512, 4) void k2_xhat(const float* __restrict__ X,
                                                  const float* __restrict__ WB,
                                                  unsigned short* __restrict__ PART) {
    __shared__ __align__(16) unsigned short Xs[128 * 72];    // [c][64n + pad8]
    __shared__ __align__(16) unsigned short WBT[128 * 72];   // [k][64n + pad8]
    int nt = blockIdx.x, b = blockIdx.y, kh = blockIdx.z;
    int r0 = nt * 256;
    int t  = threadIdx.x;
    int wave = t >> 6, lane = t & 63;
    int wm = wave >> 2, wk = wave & 3;        // wave tile: 64c x 32k of 128c x 128k
    int quad = lane >> 4, l16 = lane & 15;

    const float* xb  = X  + (size_t)b * CIN * NX;
    const float* wbb = WB + (size_t)b * NX * MODES + kh * 128;

    // staging roles: waves 4..7 stage X, waves 0..3 stage WB (transposed)
    bool isX = (t >= 256);
    int j  = t & 255;
    int xc = j & 127, xh = j >> 7;            // X: row xc, n-off xh*32 + 4q
    int kq = j & 31,  ng = j >> 5;            // WB: k-quad kq, n-groups ng

    f32x4 acc[4][2];
#pragma unroll
    for (int i = 0; i < 4; i++)
#pragma unroll
        for (int jj = 0; jj < 2; jj++) acc[i][jj] = (f32x4){0.f, 0.f, 0.f, 0.f};

    f32x4 st[8];

    // prologue: burst-issue pass 0 (8 x 16B per thread, no barrier in between)
    {
        int rs = r0;
        if (isX) {
#pragma unroll
            for (int q = 0; q < 8; q++)
                st[q] = *(const f32x4*)(xb + (size_t)xc * NX + rs + xh * 32 + 4 * q);
        } else {
#pragma unroll
            for (int g = 0; g < 2; g++)
#pragma unroll
                for (int r = 0; r < 4; r++)
                    st[g * 4 + r] = *(const f32x4*)(wbb + (size_t)(rs + g * 32 + ng * 4 + r) * MODES + 4 * kq);
        }
    }

    for (int p = 0; p < 4; p++) {
        if (p) __syncthreads();   // pass p-1 frag reads complete before overwrite
        if (isX) {
#pragma unroll
            for (int q = 0; q < 8; q++)
                *(ushort4*)(Xs + (size_t)xc * 72 + xh * 32 + 4 * q) = cvt4(st[q]);
        } else {
            // register 4x4 transpose: write 4 consecutive n at fixed k
#pragma unroll
            for (int g = 0; g < 2; g++)
#pragma unroll
                for (int j2 = 0; j2 < 4; j2++) {
                    ushort4 w;
                    w.x = f2bf(st[g * 4 + 0][j2]); w.y = f2bf(st[g * 4 + 1][j2]);
                    w.z = f2bf(st[g * 4 + 2][j2]); w.w = f2bf(st[g * 4 + 3][j2]);
                    *(ushort4*)(WBT + (size_t)(4 * kq + j2) * 72 + g * 32 + ng * 4) = w;
                }
        }
        __syncthreads();          // staging visible

        if (p < 3) {              // burst-issue pass p+1; drains across compute
            int rs = r0 + (p + 1) * 64;
            if (isX) {
#pragma unroll
                for (int q = 0; q < 8; q++)
                    st[q] = *(const f32x4*)(xb + (size_t)xc * NX + rs + xh * 32 + 4 * q);
            } else {
#pragma unroll
                for (int g = 0; g < 2; g++)
#pragma unroll
                    for (int r = 0; r < 4; r++)
                        st[g * 4 + r] = *(const f32x4*)(wbb + (size_t)(rs + g * 32 + ng * 4 + r) * MODES + 4 * kq);
            }
        }

#pragma unroll
        for (int ks = 0; ks < 2; ks++) {
            bf16x8 af[4], bfv[2];
#pragma unroll
            for (int tm = 0; tm < 4; tm++)
                af[tm] = *(const bf16x8*)(Xs + (size_t)(wm * 64 + tm * 16 + l16) * 72 + ks * 32 + quad * 8);
#pragma unroll
            for (int tn = 0; tn < 2; tn++)
                bfv[tn] = *(const bf16x8*)(WBT + (size_t)(wk * 32 + tn * 16 + l16) * 72 + ks * 32 + quad * 8);
#pragma unroll
            for (int tm = 0; tm < 4; tm++)
#pragma unroll
                for (int tn = 0; tn < 2; tn++)
                    acc[tm][tn] = __builtin_amdgcn_mfma_f32_16x16x32_bf16(af[tm], bfv[tn], acc[tm][tn], 0, 0, 0);
        }
    }

    unsigned short* pb = PART + ((size_t)b * 32 + nt) * (CIN * MODES) + kh * 128;
#pragma unroll
    for (int tm = 0; tm < 4; tm++) {
        int c = wm * 64 + tm * 16 + quad * 4;
#pragma unroll
        for (int tn = 0; tn < 2; tn++) {
            int km = wk * 32 + tn * 16 + l16;
#pragma unroll
            for (int r = 0; r < 4; r++)
                pb[(size_t)(c + r) * MODES + km] = f2bf(acc[tm][tn][r]);
        }
    }
}

// ---------------------------------------------------------------------------
// K2b: XH[b][c][k] = sum_nt PART[b][nt][c][k]   (unchanged)
// ---------------------------------------------------------------------------
__global__ __launch_bounds__(256) void k2b_red(const unsigned short* __restrict__ PART,
                                               float* __restrict__ XH) {
    int e0 = blockIdx.x * 1024 + threadIdx.x;
#pragma unroll
    for (int r = 0; r < 4; r++) {
        int e = e0 + r * 256;
        int b = e >> 15, rem = e & 32767;
        const unsigned short* p = PART + (size_t)b * 32 * (CIN * MODES) + rem;
        float acc = 0.f;
#pragma unroll
        for (int nt = 0; nt < 32; nt++) acc += bf2f(p[nt * (CIN * MODES)]);
        XH[e] = acc;
    }
}

// ---------------------------------------------------------------------------
// K3 v2: y_hat[b][o][k] = sum_i x_hat[b][i][k] * Wk[k][o][i]   (unchanged)
// ---------------------------------------------------------------------------
__global__ __launch_bounds__(256) void k3_yhat(const float* __restrict__ XH,
                                               const unsigned short* __restrict__ Wk,
                                               unsigned short* __restrict__ YH) {
    __shared__ float xs[128][8];
    int k = blockIdx.x;
    int t = threadIdx.x;
#pragma unroll
    for (int l = 0; l < 4; l++) {
        int e = l * 256 + t;
        int i = e >> 3, b = e & 7;
        xs[i][b] = XH[(size_t)b * (CIN * MODES) + (size_t)i * MODES + k];
    }
    __syncthreads();
    int o = t & 127, bh = t >> 7;
    const unsigned short* wp = Wk + (size_t)k * (CIN * COUT) + (size_t)o * CIN;
    f32x4 acc = {0.f, 0.f, 0.f, 0.f};
    for (int ii = 0; ii < 16; ii++) {
        bf16x8 wc = *(const bf16x8*)(wp + ii * 8);
#pragma unroll
        for (int jj = 0; jj < 8; jj++) {
            float w = bf2f((unsigned short)wc[jj]);
            f32x4 xv = *(const f32x4*)&xs[ii * 8 + jj][bh * 4];
            acc += w * xv;
        }
    }
#pragma unroll
    for (int r = 0; r < 4; r++)
        YH[((size_t)(bh * 4 + r) * COUT + o) * MODES + k] = f2bf(acc[r]);
}

// ---------------------------------------------------------------------------
// K4 v3: y[b][c][n] = sum_k y_hat[b][c][k] * bases[b][n][k]
// Same MLP restructure as k2 v5: 2 fat passes of K=128, 512 threads,
// 12x16B load bursts per thread per pass, 3 barriers total (was 16).
// Accumulation order over k identical to v2 -> bitwise-same Y.
// ---------------------------------------------------------------------------
__global__ __launch_bounds__(512, 4) void k4_y(const unsigned short* __restrict__ YH,
                                               const float* __restrict__ BA,
                                               float* __restrict__ Y) {
    __shared__ __align__(16) unsigned short As[128 * 136];   // [c][128k + pad8]
    __shared__ __align__(16) unsigned short Bs[128 * 136];   // [n][128k + pad8]
    int b  = blockIdx.y;
    int n0 = blockIdx.x * 128;
    int t  = threadIdx.x;
    int wave = t >> 6, lane = t & 63;
    int wm = wave >> 2, wn2 = wave & 3;       // wave tile: 64c x 32n of 128c x 128n
    int quad = lane >> 4, l16 = lane & 15;

    const unsigned short* yhb = YH + (size_t)b * COUT * MODES;
    const float* bab = BA + (size_t)b * NX * MODES + (size_t)n0 * MODES;

    int rc = t & 127, rq = t >> 7;            // payload row (c or n), k-quarter 0..3

    f32x4 acc[4][2];
#pragma unroll
    for (int i = 0; i < 4; i++)
#pragma unroll
        for (int jj = 0; jj < 2; jj++) acc[i][jj] = (f32x4){0.f, 0.f, 0.f, 0.f};

    bf16x8 av[4];   // YH payload: 4x16B = 32 k at row rc (already bf16)
    f32x4  bv[8];   // BA payload: 8x16B = 32 k at row rc

    // burst-issue pass 0 (kp = 0)
#pragma unroll
    for (int q = 0; q < 4; q++)
        av[q] = *(const bf16x8*)(yhb + (size_t)rc * MODES + rq * 32 + 8 * q);
#pragma unroll
    for (int q = 0; q < 8; q++)
        bv[q] = *(const f32x4*)(bab + (size_t)rc * MODES + rq * 32 + 4 * q);

    for (int p = 0; p < 2; p++) {
        if (p) __syncthreads();   // pass-0 frag reads complete before overwrite
#pragma unroll
        for (int q = 0; q < 4; q++)
            *(bf16x8*)(As + (size_t)rc * 136 + rq * 32 + 8 * q) = av[q];
#pragma unroll
        for (int q = 0; q < 8; q++)
            *(ushort4*)(Bs + (size_t)rc * 136 + rq * 32 + 4 * q) = cvt4(bv[q]);
        __syncthreads();          // staging visible

        if (p == 0) {             // burst-issue pass 1; drains across compute
#pragma unroll
            for (int q = 0; q < 4; q++)
                av[q] = *(const bf16x8*)(yhb + (size_t)rc * MODES + 128 + rq * 32 + 8 * q);
#pragma unroll
            for (int q = 0; q < 8; q++)
                bv[q] = *(const f32x4*)(bab + (size_t)rc * MODES + 128 + rq * 32 + 4 * q);
        }

#pragma unroll
        for (int ks = 0; ks < 4; ks++) {
            bf16x8 af[4], bfv[2];
#pragma unroll
            for (int tm = 0; tm < 4; tm++)
                af[tm] = *(const bf16x8*)(As + (size_t)(wm * 64 + tm * 16 + l16) * 136 + ks * 32 + quad * 8);
#pragma unroll
            for (int tn = 0; tn < 2; tn++)
                bfv[tn] = *(const bf16x8*)(Bs + (size_t)(wn2 * 32 + tn * 16 + l16) * 136 + ks * 32 + quad * 8);
#pragma unroll
            for (int tm = 0; tm < 4; tm++)
#pragma unroll
                for (int tn = 0; tn < 2; tn++)
                    acc[tm][tn] = __builtin_amdgcn_mfma_f32_16x16x32_bf16(af[tm], bfv[tn], acc[tm][tn], 0, 0, 0);
        }
    }

    float* yb = Y + (size_t)b * COUT * NX;
#pragma unroll
    for (int tm = 0; tm < 4; tm++) {
        int o = wm * 64 + tm * 16 + quad * 4;
#pragma unroll
        for (int tn = 0; tn < 2; tn++) {
            int n = n0 + wn2 * 32 + tn * 16 + l16;
#pragma unroll
            for (int r = 0; r < 4; r++)
                yb[(size_t)(o + r) * NX + n] = acc[tm][tn][r];
        }
    }
}

extern "C" void kernel_launch(void* const* d_in, const int* in_sizes, int n_in,
                              void* d_out, int out_size, void* d_ws, size_t ws_size,
                              hipStream_t stream) {
    const float* X  = (const float*)d_in[0];  // [8][128][8192]
    const float* WB = (const float*)d_in[1];  // [8][8192][256]
    const float* BA = (const float*)d_in[2];  // [8][8192][256]
    const float* W  = (const float*)d_in[3];  // [128][128][32]
    const float* D  = (const float*)d_in[4];  // [32][256]
    float* Y = (float*)d_out;                 // [8][128][8192]

    char* ws = (char*)d_ws;
    unsigned short* Wk   = (unsigned short*)ws;                  // 8 MB bf16 [k][o][i]
    float*          XH   = (float*)(ws + (8u << 20));            // 1 MB fp32 [b][c][k]
    unsigned short* YH   = (unsigned short*)(ws + (9u << 20));   // 0.5 MB bf16 [b][o][k]
    unsigned short* PART = (unsigned short*)(ws + (10u << 20));  // 16.75 MB bf16 [b][nt][c][k]

    k1_wk  <<<256,            256, 0, stream>>>(W, D, Wk);
    k2_xhat<<<dim3(32, 8, 2), 512, 0, stream>>>(X, WB, PART);
    k2b_red<<<256,            256, 0, stream>>>(PART, XH);
    k3_yhat<<<MODES,          256, 0, stream>>>(XH, Wk, YH);
    k4_y   <<<dim3(64, 8),    512, 0, stream>>>(YH, BA, Y);
}

// Round 3
// 219.545 us; speedup vs baseline: 1.0234x; 1.0234x over previous
//
#include <hip/hip_runtime.h>

#define B_    8
#define CIN   128
#define COUT  128
#define NX    8192
#define KMJ   32
#define MODES 256

typedef short bf16x8 __attribute__((ext_vector_type(8)));
typedef float f32x4  __attribute__((ext_vector_type(4)));

__device__ __forceinline__ float bf2f(unsigned short u) {
    union { unsigned int i; float f; } v; v.i = ((unsigned int)u) << 16; return v.f;
}
__device__ __forceinline__ unsigned short f2bf(float f) {
    union { float f; unsigned int i; } v; v.f = f;
    unsigned int x = v.i;
    return (unsigned short)((x + 0x7fffu + ((x >> 16) & 1u)) >> 16);
}
__device__ __forceinline__ bf16x8 cvt8(const float* __restrict__ p) {
    f32x4 a = *(const f32x4*)p;
    f32x4 b = *(const f32x4*)(p + 4);
    bf16x8 r;
    r[0] = (short)f2bf(a[0]); r[1] = (short)f2bf(a[1]);
    r[2] = (short)f2bf(a[2]); r[3] = (short)f2bf(a[3]);
    r[4] = (short)f2bf(b[0]); r[5] = (short)f2bf(b[1]);
    r[6] = (short)f2bf(b[2]); r[7] = (short)f2bf(b[3]);
    return r;
}
__device__ __forceinline__ ushort4 cvt4(f32x4 a) {
    ushort4 r;
    r.x = f2bf(a[0]); r.y = f2bf(a[1]); r.z = f2bf(a[2]); r.w = f2bf(a[3]);
    return r;
}

// ---------------------------------------------------------------------------
// K1 v3: Wk[k][o][i] = sum_j D[j][k] * weights[i][o][j]
// mt-split over blockIdx.y: grid 256->1024 blocks = 4 blocks/CU (occupancy).
// Same per-output math -> bitwise-same Wk.
// ---------------------------------------------------------------------------
__global__ __launch_bounds__(256) void k1_wk(const float* __restrict__ W,
                                             const float* __restrict__ D,
                                             unsigned short* __restrict__ Wk) {
    int wave = threadIdx.x >> 6, lane = threadIdx.x & 63;
    int quad = lane >> 4, l16 = lane & 15;
    int gw  = blockIdx.x * 4 + wave;
    int oi0 = gw * 16;
    int i0  = oi0 & 127, o0 = oi0 >> 7;
    bf16x8 bfrag = cvt8(W + ((size_t)(i0 + l16) * COUT + o0) * KMJ + quad * 8);
#pragma unroll
    for (int m = 0; m < 4; m++) {
        int k0 = (blockIdx.y * 4 + m) * 16;
        bf16x8 afrag;
#pragma unroll
        for (int jj = 0; jj < 8; jj++)
            afrag[jj] = (short)f2bf(D[(quad * 8 + jj) * MODES + k0 + l16]);
        f32x4 acc = {0.f, 0.f, 0.f, 0.f};
        acc = __builtin_amdgcn_mfma_f32_16x16x32_bf16(afrag, bfrag, acc, 0, 0, 0);
#pragma unroll
        for (int r = 0; r < 4; r++)
            Wk[(size_t)(k0 + quad * 4 + r) * (CIN * COUT) + oi0 + l16] = f2bf(acc[r]);
    }
}

// ---------------------------------------------------------------------------
// K2 v6: PART[b][nt][c][k] = sum_{n in nt-chunk} x[b][c][n]*wb[b][n][k]  (bf16)
//
// Round-2 post-mortem: v3/v4/v5 all ~46us. v3->v4 (+2x waves) served +34%
// bytes at constant time; v4->v5 (+2x burst depth) changed NOTHING. The
// effective BW scales with RESIDENT WAVES, not per-thread MLP (m13's 6.3TB/s
// needs ~32 waves/CU). v6: 1024-thread blocks (16 waves), grid 512 -> 2
// blocks/CU = 32 waves/CU. Registers engineered <=64 (acc[2][2]=16, st=8,
// transient frags) so both blocks fit: __launch_bounds__(1024, 8).
// kh-split now writes disjoint K-HALVES of the SAME PART slab -> PART size
// unchanged (16.7MB), k2b unchanged. 8 passes of 32n; XOR slot swizzle on
// Xs/WBT (consistent on read+write); WBT transposed writes conflict-free.
// Accumulation order (ascending 32-n chunks) identical -> bitwise-same PART.
// ---------------------------------------------------------------------------
__global__ __launch_bounds__(1024, 8) void k2_xhat(const float* __restrict__ X,
                                                   const float* __restrict__ WB,
                                                   unsigned short* __restrict__ PART) {
    __shared__ __align__(16) unsigned short Xs[128 * 40];    // [c][32n], 80B rows
    __shared__ __align__(16) unsigned short WBT[128 * 40];   // [k][32n], 80B rows
    int nt = blockIdx.x, b = blockIdx.y, kh = blockIdx.z;
    int r0 = nt * 256;
    int t  = threadIdx.x;
    int wave = t >> 6, lane = t & 63;
    int wm = wave >> 2, wk = wave & 3;     // 16 waves: 4x4 over 128c x 128k
    int quad = lane >> 4, l16 = lane & 15;
    int sw = quad ^ (l16 & 3);             // slot swizzle for frag reads

    const float* xb  = X  + (size_t)b * CIN * NX;
    const float* wbb = WB + (size_t)b * NX * MODES + kh * 128;

    bool isX = (t >= 512);                 // waves 8..15 stage X, 0..7 stage WB
    int j  = t & 511;
    int xr = j >> 2, xseg = j & 3;         // X: row xr, cols xseg*8..+7
    int kq = j >> 4, np = j & 15;          // WB: cols 4kq..+3, rows 2np,2np+1

    const float* gx = xb + (size_t)xr * NX + r0 + xseg * 8;
    const float* gw = wbb + (size_t)(r0 + 2 * np) * MODES + 4 * kq;
    unsigned short* xw = Xs + xr * 40 + ((xseg ^ (xr & 3)) << 3);

    f32x4 acc[2][2];
#pragma unroll
    for (int i = 0; i < 2; i++)
#pragma unroll
        for (int jj = 0; jj < 2; jj++) acc[i][jj] = (f32x4){0.f, 0.f, 0.f, 0.f};

    f32x4 st0, st1;
    if (isX) { st0 = *(const f32x4*)gx; st1 = *(const f32x4*)(gx + 4); }
    else     { st0 = *(const f32x4*)gw; st1 = *(const f32x4*)(gw + MODES); }

    for (int p = 0; p < 8; p++) {
        if (p) __syncthreads();            // prev pass frag reads complete
        if (isX) {
            *(ushort4*)xw       = cvt4(st0);
            *(ushort4*)(xw + 4) = cvt4(st1);
        } else {
            // transposed: for each of 4 k's, pack (n=2np, n=2np+1) as one dword
#pragma unroll
            for (int jj = 0; jj < 4; jj++) {
                int k = 4 * kq + jj;
                unsigned int w = (unsigned int)f2bf(st0[jj]) |
                                 ((unsigned int)f2bf(st1[jj]) << 16);
                *(unsigned int*)(WBT + k * 40 + (((np >> 2) ^ (k & 3)) << 3) + ((np & 3) << 1)) = w;
            }
        }
        __syncthreads();                   // staging visible

        if (p < 7) {                       // issue next pass; drains over MFMA + barrier
            if (isX) { gx += 32;          st0 = *(const f32x4*)gx; st1 = *(const f32x4*)(gx + 4); }
            else     { gw += 32 * MODES;  st0 = *(const f32x4*)gw; st1 = *(const f32x4*)(gw + MODES); }
        }

        bf16x8 af[2], bfv[2];
#pragma unroll
        for (int tm = 0; tm < 2; tm++)
            af[tm] = *(const bf16x8*)(Xs + (wm * 32 + tm * 16 + l16) * 40 + (sw << 3));
#pragma unroll
        for (int tn = 0; tn < 2; tn++)
            bfv[tn] = *(const bf16x8*)(WBT + (wk * 32 + tn * 16 + l16) * 40 + (sw << 3));
#pragma unroll
        for (int tm = 0; tm < 2; tm++)
#pragma unroll
            for (int tn = 0; tn < 2; tn++)
                acc[tm][tn] = __builtin_amdgcn_mfma_f32_16x16x32_bf16(af[tm], bfv[tn], acc[tm][tn], 0, 0, 0);
    }

    unsigned short* pb = PART + ((size_t)b * 32 + nt) * (CIN * MODES) + kh * 128;
#pragma unroll
    for (int tm = 0; tm < 2; tm++) {
        int c = wm * 32 + tm * 16 + quad * 4;
#pragma unroll
        for (int tn = 0; tn < 2; tn++) {
            int km = wk * 32 + tn * 16 + l16;
#pragma unroll
            for (int r = 0; r < 4; r++)
                pb[(size_t)(c + r) * MODES + km] = f2bf(acc[tm][tn][r]);
        }
    }
}

// ---------------------------------------------------------------------------
// K2b v2: XH[b][c][k] = sum_nt PART[b][nt][c][k]
// grid 256->1024 (4 blocks/CU, 16 waves), 1 output/thread, 32 independent
// loads burst. Same nt order -> bitwise-same XH.
// ---------------------------------------------------------------------------
__global__ __launch_bounds__(256) void k2b_red(const unsigned short* __restrict__ PART,
                                               float* __restrict__ XH) {
    int e = blockIdx.x * 256 + threadIdx.x;            // 0..262143
    const unsigned short* p = PART + (size_t)(e >> 15) * 32 * (CIN * MODES) + (e & 32767);
    float acc = 0.f;
#pragma unroll
    for (int nt = 0; nt < 32; nt++) acc += bf2f(p[nt * (CIN * MODES)]);
    XH[e] = acc;
}

// ---------------------------------------------------------------------------
// K3 v3: y_hat[b][o][k] = sum_i x_hat[b][i][k] * Wk[k][o][i]
// o-half split (grid (256,2)) -> 2 blocks/CU; Wk row burst-loaded into 16
// regs up front (was serial 16-iter load+FMA chain). Same per-output ii,jj
// order -> bitwise-same YH.
// ---------------------------------------------------------------------------
__global__ __launch_bounds__(256, 2) void k3_yhat(const float* __restrict__ XH,
                                                  const unsigned short* __restrict__ Wk,
                                                  unsigned short* __restrict__ YH) {
    __shared__ float xs[128][8];
    int k = blockIdx.x, oh = blockIdx.y;
    int t = threadIdx.x;
#pragma unroll
    for (int l = 0; l < 4; l++) {
        int e = l * 256 + t;                   // 0..1023
        int i = e >> 3, bb = e & 7;
        xs[i][bb] = XH[(size_t)bb * (CIN * MODES) + (size_t)i * MODES + k];
    }
    int o = oh * 64 + (t & 63), bq = t >> 6;   // bq 0..3 -> b = 2bq, 2bq+1
    const unsigned short* wp = Wk + (size_t)k * (CIN * COUT) + (size_t)o * CIN;
    bf16x8 wc[16];
#pragma unroll
    for (int ii = 0; ii < 16; ii++)
        wc[ii] = *(const bf16x8*)(wp + ii * 8); // burst 16x16B, no dependent chain
    __syncthreads();
    float a0 = 0.f, a1 = 0.f;
#pragma unroll
    for (int ii = 0; ii < 16; ii++)
#pragma unroll
        for (int jj = 0; jj < 8; jj++) {
            float w = bf2f((unsigned short)wc[ii][jj]);
            int i = ii * 8 + jj;
            a0 += w * xs[i][bq * 2];
            a1 += w * xs[i][bq * 2 + 1];
        }
    YH[((size_t)(bq * 2)     * COUT + o) * MODES + k] = f2bf(a0);
    YH[((size_t)(bq * 2 + 1) * COUT + o) * MODES + k] = f2bf(a1);
}

// ---------------------------------------------------------------------------
// K4 v4: y[b][c][n] = sum_k y_hat[b][c][k] * bases[b][n][k]
// Same restructure as k2 v6: 1024 thr (16 waves), grid (128n-tiles... (64,8)
// = 512 blocks -> 2 blocks/CU = 32 waves. 8 passes of 32k, LDS 20KB,
// XOR slot swizzle. k-chunk order ascending, same as v2/v3 -> bitwise-same Y.
// ---------------------------------------------------------------------------
__global__ __launch_bounds__(1024, 8) void k4_y(const unsigned short* __restrict__ YH,
                                                const float* __restrict__ BA,
                                                float* __restrict__ Y) {
    __shared__ __align__(16) unsigned short As[128 * 40];   // [c][32k]
    __shared__ __align__(16) unsigned short Bs[128 * 40];   // [n][32k]
    int b  = blockIdx.y;
    int n0 = blockIdx.x * 128;
    int t  = threadIdx.x;
    int wave = t >> 6, lane = t & 63;
    int wm = wave >> 2, wn = wave & 3;     // 16 waves: 4x4 over 128c x 128n
    int quad = lane >> 4, l16 = lane & 15;
    int sw = quad ^ (l16 & 3);

    const unsigned short* yhb = YH + (size_t)b * COUT * MODES;
    const float* bab = BA + (size_t)b * NX * MODES + (size_t)n0 * MODES;

    bool isA = (t < 512);                  // waves 0..7 stage YH, 8..15 stage BA
    int j  = t & 511;
    int rr = j >> 2, seg = j & 3;          // row rr, cols seg*8..+7
    int ssw = (seg ^ (rr & 3)) << 3;

    const unsigned short* ga = yhb + (size_t)rr * MODES + seg * 8;
    const float* gb = bab + (size_t)rr * MODES + seg * 8;

    f32x4 acc[2][2];
#pragma unroll
    for (int i = 0; i < 2; i++)
#pragma unroll
        for (int jj = 0; jj < 2; jj++) acc[i][jj] = (f32x4){0.f, 0.f, 0.f, 0.f};

    bf16x8 sa; f32x4 sb0, sb1;
    if (isA) sa = *(const bf16x8*)ga;
    else { sb0 = *(const f32x4*)gb; sb1 = *(const f32x4*)(gb + 4); }

    for (int p = 0; p < 8; p++) {
        if (p) __syncthreads();
        if (isA) {
            *(bf16x8*)(As + rr * 40 + ssw) = sa;
        } else {
            bf16x8 v;
            v[0] = (short)f2bf(sb0[0]); v[1] = (short)f2bf(sb0[1]);
            v[2] = (short)f2bf(sb0[2]); v[3] = (short)f2bf(sb0[3]);
            v[4] = (short)f2bf(sb1[0]); v[5] = (short)f2bf(sb1[1]);
            v[6] = (short)f2bf(sb1[2]); v[7] = (short)f2bf(sb1[3]);
            *(bf16x8*)(Bs + rr * 40 + ssw) = v;
        }
        __syncthreads();

        if (p < 7) {
            if (isA) { ga += 32; sa = *(const bf16x8*)ga; }
            else     { gb += 32; sb0 = *(const f32x4*)gb; sb1 = *(const f32x4*)(gb + 4); }
        }

        bf16x8 af[2], bfv[2];
#pragma unroll
        for (int tm = 0; tm < 2; tm++)
            af[tm] = *(const bf16x8*)(As + (wm * 32 + tm * 16 + l16) * 40 + (sw << 3));
#pragma unroll
        for (int tn = 0; tn < 2; tn++)
            bfv[tn] = *(const bf16x8*)(Bs + (wn * 32 + tn * 16 + l16) * 40 + (sw << 3));
#pragma unroll
        for (int tm = 0; tm < 2; tm++)
#pragma unroll
            for (int tn = 0; tn < 2; tn++)
                acc[tm][tn] = __builtin_amdgcn_mfma_f32_16x16x32_bf16(af[tm], bfv[tn], acc[tm][tn], 0, 0, 0);
    }

    float* yb = Y + (size_t)b * COUT * NX;
#pragma unroll
    for (int tm = 0; tm < 2; tm++) {
        int o = wm * 32 + tm * 16 + quad * 4;
#pragma unroll
        for (int tn = 0; tn < 2; tn++) {
            int n = n0 + wn * 32 + tn * 16 + l16;
#pragma unroll
            for (int r = 0; r < 4; r++)
                yb[(size_t)(o + r) * NX + n] = acc[tm][tn][r];
        }
    }
}

extern "C" void kernel_launch(void* const* d_in, const int* in_sizes, int n_in,
                              void* d_out, int out_size, void* d_ws, size_t ws_size,
                              hipStream_t stream) {
    const float* X  = (const float*)d_in[0];  // [8][128][8192]
    const float* WB = (const float*)d_in[1];  // [8][8192][256]
    const float* BA = (const float*)d_in[2];  // [8][8192][256]
    const float* W  = (const float*)d_in[3];  // [128][128][32]
    const float* D  = (const float*)d_in[4];  // [32][256]
    float* Y = (float*)d_out;                 // [8][128][8192]

    char* ws = (char*)d_ws;
    unsigned short* Wk   = (unsigned short*)ws;                  // 8 MB bf16 [k][o][i]
    float*          XH   = (float*)(ws + (8u << 20));            // 1 MB fp32 [b][c][k]
    unsigned short* YH   = (unsigned short*)(ws + (9u << 20));   // 0.5 MB bf16 [b][o][k]
    unsigned short* PART = (unsigned short*)(ws + (10u << 20));  // 16.75 MB bf16 [b][nt][c][k]

    k1_wk  <<<dim3(256, 4),   256,  0, stream>>>(W, D, Wk);
    k2_xhat<<<dim3(32, 8, 2), 1024, 0, stream>>>(X, WB, PART);
    k2b_red<<<1024,           256,  0, stream>>>(PART, XH);
    k3_yhat<<<dim3(256, 2),   256,  0, stream>>>(XH, Wk, YH);
    k4_y   <<<dim3(64, 8),    1024, 0, stream>>>(YH, BA, Y);
}